// Round 1
// baseline (1197.285 us; speedup 1.0000x reference)
//
#include <hip/hip_runtime.h>
#include <hip/hip_fp16.h>
#include <stdint.h>

// Problem constants
#define TT 4096      // total tokens (B*T)
#define DD 2048      // model dim
#define FF 2048      // expert hidden dim
#define EE 8         // experts
#define BM 128
#define BK 32
#define MAXPAD 9216  // 8192 pairs + 8*128 pad

typedef _Float16 half8 __attribute__((ext_vector_type(8)));
typedef float f32x4 __attribute__((ext_vector_type(4)));

// ---------------- utility kernels ----------------

__global__ void zero_cnt_kernel(int* cnt) {
    if (threadIdx.x < EE) cnt[threadIdx.x] = 0;
}

__global__ void cvt_f32_f16_kernel(const float* __restrict__ src,
                                   _Float16* __restrict__ dst, int n) {
    int i = (blockIdx.x * blockDim.x + threadIdx.x) * 4;
    if (i >= n) return;
    float4 v = *(const float4*)(src + i);
    union { _Float16 h[4]; uint2 u; } p;
    p.h[0] = (_Float16)v.x; p.h[1] = (_Float16)v.y;
    p.h[2] = (_Float16)v.z; p.h[3] = (_Float16)v.w;
    *(uint2*)(dst + i) = p.u;
}

// Router: scores = sigmoid(x @ router_DE), top-2, append to per-expert lists.
__global__ void router_topk_kernel(const float* __restrict__ x,
                                   const float* __restrict__ rDE,
                                   int* __restrict__ cnt,
                                   int* __restrict__ tok_list,
                                   float* __restrict__ gate_list) {
    int t = blockIdx.x;
    __shared__ float red[256 * EE];
    float part[EE];
#pragma unroll
    for (int e = 0; e < EE; e++) part[e] = 0.f;
    const float* xr = x + (size_t)t * DD;
    for (int d = threadIdx.x; d < DD; d += 256) {
        float xv = xr[d];
        const float* rr = rDE + (size_t)d * EE;
#pragma unroll
        for (int e = 0; e < EE; e++) part[e] += xv * rr[e];
    }
#pragma unroll
    for (int e = 0; e < EE; e++) red[threadIdx.x * EE + e] = part[e];
    __syncthreads();
    for (int s = 128; s > 0; s >>= 1) {
        if (threadIdx.x < s) {
#pragma unroll
            for (int e = 0; e < EE; e++)
                red[threadIdx.x * EE + e] += red[(threadIdx.x + s) * EE + e];
        }
        __syncthreads();
    }
    if (threadIdx.x == 0) {
        float sc[EE];
#pragma unroll
        for (int e = 0; e < EE; e++) sc[e] = 1.f / (1.f + expf(-red[e]));
        int i0 = 0;
        for (int e = 1; e < EE; e++) if (sc[e] > sc[i0]) i0 = e;
        int i1 = -1;
        for (int e = 0; e < EE; e++) {
            if (e == i0) continue;
            if (i1 < 0 || sc[e] > sc[i1]) i1 = e;
        }
        int p0 = atomicAdd(&cnt[i0], 1);
        tok_list[i0 * TT + p0] = t; gate_list[i0 * TT + p0] = sc[i0];
        int p1 = atomicAdd(&cnt[i1], 1);
        tok_list[i1 * TT + p1] = t; gate_list[i1 * TT + p1] = sc[i1];
    }
}

// Exclusive 128-padded offsets
__global__ void scan_offsets_kernel(const int* __restrict__ cnt, int* __restrict__ poff) {
    if (threadIdx.x == 0) {
        int off = 0;
        for (int e = 0; e < EE; e++) {
            poff[e] = off;
            off += ((cnt[e] + 127) >> 7) << 7;
        }
        poff[EE] = off;
    }
}

// Gather gate-scaled token rows into padded per-expert groups (fp16).
__global__ void gather_rows_kernel(const float* __restrict__ x,
                                   const int* __restrict__ cnt,
                                   const int* __restrict__ poff,
                                   const int* __restrict__ tok_list,
                                   const float* __restrict__ gate_list,
                                   _Float16* __restrict__ gath,
                                   int* __restrict__ rowinfo) {
    int b = blockIdx.x;
    if (b >= poff[EE]) return;
    int e = 0;
    while (b >= poff[e + 1]) e++;
    int i = b - poff[e];
    _Float16* dst = gath + (size_t)b * DD;
    if (i < cnt[e]) {
        int t = tok_list[e * TT + i];
        float g = gate_list[e * TT + i];
        if (threadIdx.x == 0) rowinfo[b] = t;
        const float* src = x + (size_t)t * DD;
        for (int d = threadIdx.x * 4; d < DD; d += 1024) {
            float4 v = *(const float4*)(src + d);
            union { _Float16 h[4]; uint2 u; } p;
            p.h[0] = (_Float16)(v.x * g); p.h[1] = (_Float16)(v.y * g);
            p.h[2] = (_Float16)(v.z * g); p.h[3] = (_Float16)(v.w * g);
            *(uint2*)(dst + d) = p.u;
        }
    } else {
        if (threadIdx.x == 0) rowinfo[b] = -1;
        uint2 z; z.x = 0u; z.y = 0u;
        for (int d = threadIdx.x * 4; d < DD; d += 1024)
            *(uint2*)(dst + d) = z;
    }
}

// ---------------- GEMM kernels ----------------
// C = A(M x 2048) @ W^T pattern: both operands row-major with K contiguous.
// fragment layouts (gfx950, 16x16x32): A/B: elem k = quad*8+j, m/n = lane&15
//                                      C/D: col = lane&15, row = quad*4+reg

// w13 GEMM: computes both halves (y0: W rows [0,F), y1: W rows [F,2F)) and
// writes act = silu(y0)*y1 as fp16.  If cnt!=nullptr: grouped (per-expert) mode.
__global__ __launch_bounds__(256, 2)
void gemm_w13_swiglu_kernel(const _Float16* __restrict__ A,
                            const _Float16* __restrict__ W13,
                            _Float16* __restrict__ act,
                            const int* __restrict__ cnt,
                            const int* __restrict__ poff) {
    int row_base;
    const _Float16* w;
    if (cnt) {
        int e = blockIdx.z;
        int c = cnt[e];
        int mloc = blockIdx.y * BM;
        if (mloc >= c) return;
        row_base = poff[e] + mloc;
        w = W13 + (size_t)e * (2 * FF) * DD;
    } else {
        row_base = blockIdx.y * BM;
        w = W13;
    }
    int n_base = blockIdx.x * 128;

    __shared__ _Float16 lds[128 * BK * 3];  // A | B0 | B1 = 24 KB

    const _Float16* srcA  = A + (size_t)row_base * DD;
    const _Float16* srcB0 = w + (size_t)n_base * DD;
    const _Float16* srcB1 = w + (size_t)(FF + n_base) * DD;

    int lane = threadIdx.x & 63;
    int w_id = threadIdx.x >> 6;
    int wm = (w_id >> 1) * 64;
    int wn = (w_id & 1) * 64;
    int quad = lane >> 4;
    int l15 = lane & 15;

    f32x4 acc0[4][4], acc1[4][4];
    f32x4 z4 = {0.f, 0.f, 0.f, 0.f};
#pragma unroll
    for (int m = 0; m < 4; m++)
#pragma unroll
        for (int n = 0; n < 4; n++) { acc0[m][n] = z4; acc1[m][n] = z4; }

    for (int kt = 0; kt < DD / BK; ++kt) {
        int k0 = kt * BK;
#pragma unroll
        for (int j = 0; j < 6; ++j) {
            int c = j * 256 + threadIdx.x;  // 0..1535 chunk of 8 halves
            int local = c & 511;
            int r = local >> 2;
            int col = (local & 3) * 8;
            const _Float16* src = (j < 2) ? srcA : (j < 4) ? srcB0 : srcB1;
            uint4 v = *(const uint4*)(src + (size_t)r * DD + k0 + col);
            *(uint4*)(&lds[c * 8]) = v;
        }
        __syncthreads();

        half8 a[4], b0[4], b1[4];
#pragma unroll
        for (int m = 0; m < 4; m++)
            a[m] = *(const half8*)(&lds[(wm + m * 16 + l15) * BK + quad * 8]);
#pragma unroll
        for (int n = 0; n < 4; n++) {
            b0[n] = *(const half8*)(&lds[4096 + (wn + n * 16 + l15) * BK + quad * 8]);
            b1[n] = *(const half8*)(&lds[8192 + (wn + n * 16 + l15) * BK + quad * 8]);
        }
#pragma unroll
        for (int m = 0; m < 4; m++)
#pragma unroll
            for (int n = 0; n < 4; n++) {
                acc0[m][n] = __builtin_amdgcn_mfma_f32_16x16x32_f16(a[m], b0[n], acc0[m][n], 0, 0, 0);
                acc1[m][n] = __builtin_amdgcn_mfma_f32_16x16x32_f16(a[m], b1[n], acc1[m][n], 0, 0, 0);
            }
        __syncthreads();
    }

#pragma unroll
    for (int m = 0; m < 4; m++)
#pragma unroll
        for (int n = 0; n < 4; n++)
#pragma unroll
            for (int r = 0; r < 4; r++) {
                int row = row_base + wm + m * 16 + quad * 4 + r;
                int col = n_base + wn + n * 16 + l15;
                float y0 = acc0[m][n][r];
                float y1 = acc1[m][n][r];
                float v = y0 / (1.f + __expf(-y0)) * y1;
                act[(size_t)row * FF + col] = (_Float16)v;
            }
}

// w2 GEMM: C = act(M x F) @ W2(N x F)^T -> fp32 out.
// rowinfo==nullptr: plain store with row==token. else: atomicAdd scatter.
__global__ __launch_bounds__(256, 2)
void gemm_w2_kernel(const _Float16* __restrict__ Aact,
                    const _Float16* __restrict__ W2,
                    float* __restrict__ out,
                    const int* __restrict__ cnt,
                    const int* __restrict__ poff,
                    const int* __restrict__ rowinfo) {
    int row_base;
    const _Float16* w;
    if (cnt) {
        int e = blockIdx.z;
        int c = cnt[e];
        int mloc = blockIdx.y * BM;
        if (mloc >= c) return;
        row_base = poff[e] + mloc;
        w = W2 + (size_t)e * DD * FF;
    } else {
        row_base = blockIdx.y * BM;
        w = W2;
    }
    int n_base = blockIdx.x * 128;

    __shared__ _Float16 lds[128 * BK * 2];  // A | B = 16 KB

    const _Float16* srcA = Aact + (size_t)row_base * FF;
    const _Float16* srcB = w + (size_t)n_base * FF;

    int lane = threadIdx.x & 63;
    int w_id = threadIdx.x >> 6;
    int wm = (w_id >> 1) * 64;
    int wn = (w_id & 1) * 64;
    int quad = lane >> 4;
    int l15 = lane & 15;

    f32x4 acc[4][4];
    f32x4 z4 = {0.f, 0.f, 0.f, 0.f};
#pragma unroll
    for (int m = 0; m < 4; m++)
#pragma unroll
        for (int n = 0; n < 4; n++) acc[m][n] = z4;

    for (int kt = 0; kt < FF / BK; ++kt) {
        int k0 = kt * BK;
#pragma unroll
        for (int j = 0; j < 4; ++j) {
            int c = j * 256 + threadIdx.x;  // 0..1023
            int local = c & 511;
            int r = local >> 2;
            int col = (local & 3) * 8;
            const _Float16* src = (j < 2) ? srcA : srcB;
            uint4 v = *(const uint4*)(src + (size_t)r * FF + k0 + col);
            *(uint4*)(&lds[c * 8]) = v;
        }
        __syncthreads();

        half8 a[4], b[4];
#pragma unroll
        for (int m = 0; m < 4; m++)
            a[m] = *(const half8*)(&lds[(wm + m * 16 + l15) * BK + quad * 8]);
#pragma unroll
        for (int n = 0; n < 4; n++)
            b[n] = *(const half8*)(&lds[4096 + (wn + n * 16 + l15) * BK + quad * 8]);
#pragma unroll
        for (int m = 0; m < 4; m++)
#pragma unroll
            for (int n = 0; n < 4; n++)
                acc[m][n] = __builtin_amdgcn_mfma_f32_16x16x32_f16(a[m], b[n], acc[m][n], 0, 0, 0);
        __syncthreads();
    }

#pragma unroll
    for (int m = 0; m < 4; m++)
#pragma unroll
        for (int n = 0; n < 4; n++)
#pragma unroll
            for (int r = 0; r < 4; r++) {
                int row = row_base + wm + m * 16 + quad * 4 + r;
                int col = n_base + wn + n * 16 + l15;
                float v = acc[m][n][r];
                if (rowinfo) {
                    int t = rowinfo[row];
                    if (t >= 0) atomicAdd(&out[(size_t)t * DD + col], v);
                } else {
                    out[(size_t)row * DD + col] = v;
                }
            }
}

// ---------------- launch ----------------

extern "C" void kernel_launch(void* const* d_in, const int* in_sizes, int n_in,
                              void* d_out, int out_size, void* d_ws, size_t ws_size,
                              hipStream_t stream) {
    const float* x     = (const float*)d_in[0];   // 4096 x 2048
    const float* rDE   = (const float*)d_in[1];   // 2048 x 8
    const float* sw13  = (const float*)d_in[2];   // 4096 x 2048
    const float* sw2   = (const float*)d_in[3];   // 2048 x 2048
    const float* rw13  = (const float*)d_in[4];   // 8 x 4096 x 2048
    const float* rw2   = (const float*)d_in[5];   // 8 x 2048 x 2048
    float* out = (float*)d_out;

    char* ws = (char*)d_ws;
    size_t off = 0;
    auto alloc = [&](size_t bytes) {
        char* p = ws + off;
        off += (bytes + 255) & ~(size_t)255;
        return p;
    };
    _Float16* xh    = (_Float16*)alloc((size_t)TT * DD * 2);
    _Float16* sw13h = (_Float16*)alloc((size_t)2 * FF * DD * 2);
    _Float16* sw2h  = (_Float16*)alloc((size_t)DD * FF * 2);
    _Float16* rw13h = (_Float16*)alloc((size_t)EE * 2 * FF * DD * 2);
    _Float16* rw2h  = (_Float16*)alloc((size_t)EE * DD * FF * 2);
    _Float16* acts  = (_Float16*)alloc((size_t)TT * FF * 2);
    _Float16* gath  = (_Float16*)alloc((size_t)MAXPAD * DD * 2);
    _Float16* actr  = (_Float16*)alloc((size_t)MAXPAD * FF * 2);
    int* cnt        = (int*)alloc(EE * 4);
    int* poff       = (int*)alloc((EE + 1) * 4);
    int* tok_list   = (int*)alloc((size_t)EE * TT * 4);
    float* gate_list= (float*)alloc((size_t)EE * TT * 4);
    int* rowinfo    = (int*)alloc((size_t)MAXPAD * 4);

    zero_cnt_kernel<<<1, 64, 0, stream>>>(cnt);

    // fp32 -> fp16 conversions
    auto cvt = [&](const float* s, _Float16* d, int n) {
        cvt_f32_f16_kernel<<<(n / 4 + 255) / 256, 256, 0, stream>>>(s, d, n);
    };
    cvt(x,    xh,    TT * DD);
    cvt(sw13, sw13h, 2 * FF * DD);
    cvt(sw2,  sw2h,  DD * FF);
    cvt(rw13, rw13h, EE * 2 * FF * DD);
    cvt(rw2,  rw2h,  EE * DD * FF);

    router_topk_kernel<<<TT, 256, 0, stream>>>(x, rDE, cnt, tok_list, gate_list);
    scan_offsets_kernel<<<1, 64, 0, stream>>>(cnt, poff);
    gather_rows_kernel<<<MAXPAD, 256, 0, stream>>>(x, cnt, poff, tok_list, gate_list,
                                                   gath, rowinfo);

    // shared expert
    gemm_w13_swiglu_kernel<<<dim3(FF / 128, TT / 128, 1), 256, 0, stream>>>(
        xh, sw13h, acts, nullptr, nullptr);
    gemm_w2_kernel<<<dim3(DD / 128, TT / 128, 1), 256, 0, stream>>>(
        acts, sw2h, out, nullptr, nullptr, nullptr);

    // routed experts (grouped, early-exit tiles), scatter-add on top of shared out
    gemm_w13_swiglu_kernel<<<dim3(FF / 128, TT / 128, EE), 256, 0, stream>>>(
        gath, rw13h, actr, cnt, poff);
    gemm_w2_kernel<<<dim3(DD / 128, TT / 128, EE), 256, 0, stream>>>(
        actr, rw2h, out, cnt, poff, rowinfo);
}

// Round 2
// 1188.077 us; speedup vs baseline: 1.0078x; 1.0078x over previous
//
#include <hip/hip_runtime.h>
#include <hip/hip_fp16.h>
#include <stdint.h>

// Problem constants
#define TT 4096      // total tokens (B*T)
#define DD 2048      // model dim
#define FF 2048      // expert hidden dim
#define EE 8         // experts
#define BM 128
#define BK 32
#define MAXPAD 9216  // 8192 pairs + 8*128 pad

typedef _Float16 half8 __attribute__((ext_vector_type(8)));
typedef float f32x4 __attribute__((ext_vector_type(4)));

// Direct HBM -> LDS DMA, 16 B per lane, wave-uniform LDS base + lane*16.
__device__ inline void gld_lds16(const _Float16* g, _Float16* l) {
    __builtin_amdgcn_global_load_lds(
        (const __attribute__((address_space(1))) uint32_t*)g,
        (__attribute__((address_space(3))) uint32_t*)l, 16, 0, 0);
}

// ---------------- utility kernels ----------------

__global__ void zero_cnt_kernel(int* cnt) {
    if (threadIdx.x < EE) cnt[threadIdx.x] = 0;
}

__global__ void cvt_f32_f16_kernel(const float* __restrict__ src,
                                   _Float16* __restrict__ dst, int n) {
    int i = (blockIdx.x * blockDim.x + threadIdx.x) * 4;
    if (i >= n) return;
    float4 v = *(const float4*)(src + i);
    union { _Float16 h[4]; uint2 u; } p;
    p.h[0] = (_Float16)v.x; p.h[1] = (_Float16)v.y;
    p.h[2] = (_Float16)v.z; p.h[3] = (_Float16)v.w;
    *(uint2*)(dst + i) = p.u;
}

// Router: scores = sigmoid(x @ router_DE), top-2, append to per-expert lists.
__global__ void router_topk_kernel(const float* __restrict__ x,
                                   const float* __restrict__ rDE,
                                   int* __restrict__ cnt,
                                   int* __restrict__ tok_list,
                                   float* __restrict__ gate_list) {
    int t = blockIdx.x;
    __shared__ float red[256 * EE];
    float part[EE];
#pragma unroll
    for (int e = 0; e < EE; e++) part[e] = 0.f;
    const float* xr = x + (size_t)t * DD;
    for (int d = threadIdx.x; d < DD; d += 256) {
        float xv = xr[d];
        const float* rr = rDE + (size_t)d * EE;
#pragma unroll
        for (int e = 0; e < EE; e++) part[e] += xv * rr[e];
    }
#pragma unroll
    for (int e = 0; e < EE; e++) red[threadIdx.x * EE + e] = part[e];
    __syncthreads();
    for (int s = 128; s > 0; s >>= 1) {
        if (threadIdx.x < s) {
#pragma unroll
            for (int e = 0; e < EE; e++)
                red[threadIdx.x * EE + e] += red[(threadIdx.x + s) * EE + e];
        }
        __syncthreads();
    }
    if (threadIdx.x == 0) {
        float sc[EE];
#pragma unroll
        for (int e = 0; e < EE; e++) sc[e] = 1.f / (1.f + expf(-red[e]));
        int i0 = 0;
        for (int e = 1; e < EE; e++) if (sc[e] > sc[i0]) i0 = e;
        int i1 = -1;
        for (int e = 0; e < EE; e++) {
            if (e == i0) continue;
            if (i1 < 0 || sc[e] > sc[i1]) i1 = e;
        }
        int p0 = atomicAdd(&cnt[i0], 1);
        tok_list[i0 * TT + p0] = t; gate_list[i0 * TT + p0] = sc[i0];
        int p1 = atomicAdd(&cnt[i1], 1);
        tok_list[i1 * TT + p1] = t; gate_list[i1 * TT + p1] = sc[i1];
    }
}

// Exclusive 128-padded offsets
__global__ void scan_offsets_kernel(const int* __restrict__ cnt, int* __restrict__ poff) {
    if (threadIdx.x == 0) {
        int off = 0;
        for (int e = 0; e < EE; e++) {
            poff[e] = off;
            off += ((cnt[e] + 127) >> 7) << 7;
        }
        poff[EE] = off;
    }
}

// Gather gate-scaled token rows into padded per-expert groups (fp16).
__global__ void gather_rows_kernel(const float* __restrict__ x,
                                   const int* __restrict__ cnt,
                                   const int* __restrict__ poff,
                                   const int* __restrict__ tok_list,
                                   const float* __restrict__ gate_list,
                                   _Float16* __restrict__ gath,
                                   int* __restrict__ rowinfo) {
    int b = blockIdx.x;
    if (b >= poff[EE]) return;
    int e = 0;
    while (b >= poff[e + 1]) e++;
    int i = b - poff[e];
    _Float16* dst = gath + (size_t)b * DD;
    if (i < cnt[e]) {
        int t = tok_list[e * TT + i];
        float g = gate_list[e * TT + i];
        if (threadIdx.x == 0) rowinfo[b] = t;
        const float* src = x + (size_t)t * DD;
        for (int d = threadIdx.x * 4; d < DD; d += 1024) {
            float4 v = *(const float4*)(src + d);
            union { _Float16 h[4]; uint2 u; } p;
            p.h[0] = (_Float16)(v.x * g); p.h[1] = (_Float16)(v.y * g);
            p.h[2] = (_Float16)(v.z * g); p.h[3] = (_Float16)(v.w * g);
            *(uint2*)(dst + d) = p.u;
        }
    } else {
        if (threadIdx.x == 0) rowinfo[b] = -1;
        uint2 z; z.x = 0u; z.y = 0u;
        for (int d = threadIdx.x * 4; d < DD; d += 1024)
            *(uint2*)(dst + d) = z;
    }
}

// ---------------- GEMM kernels ----------------
// C = A(M x 2048) @ W^T pattern: both operands row-major with K contiguous.
// fragment layouts (gfx950, 16x16x32): A/B: elem k = quad*8+j, m/n = lane&15
//                                      C/D: col = lane&15, row = quad*4+reg
// Staging: global_load_lds width=16 (m97 pattern): each wave DMAs 1 KB chunks,
// LDS layout is chunk-order lane-contiguous (wave-uniform base + lane*16).

// w13 GEMM: computes both halves (y0: W rows [0,F), y1: W rows [F,2F)) and
// writes act = silu(y0)*y1 as fp16.  If cnt!=nullptr: grouped (per-expert) mode.
__global__ __launch_bounds__(256, 2)
void gemm_w13_swiglu_kernel(const _Float16* __restrict__ A,
                            const _Float16* __restrict__ W13,
                            _Float16* __restrict__ act,
                            const int* __restrict__ cnt,
                            const int* __restrict__ poff) {
    int row_base;
    const _Float16* w;
    if (cnt) {
        int e = blockIdx.z;
        int c = cnt[e];
        int mloc = blockIdx.y * BM;
        if (mloc >= c) return;
        row_base = poff[e] + mloc;
        w = W13 + (size_t)e * (2 * FF) * DD;
    } else {
        row_base = blockIdx.y * BM;
        w = W13;
    }
    int n_base = blockIdx.x * 128;

    __shared__ _Float16 lds[128 * BK * 3];  // A | B0 | B1 = 24 KB

    const _Float16* srcA  = A + (size_t)row_base * DD;
    const _Float16* srcB0 = w + (size_t)n_base * DD;
    const _Float16* srcB1 = w + (size_t)(FF + n_base) * DD;

    int lane = threadIdx.x & 63;
    int wv = threadIdx.x >> 6;
    int wm = (wv >> 1) * 64;
    int wn = (wv & 1) * 64;
    int quad = lane >> 4;
    int l15 = lane & 15;
    int ldr = lane >> 2;          // row-within-chunk for staging
    int ldc = (lane & 3) * 8;     // col (halves) for staging

    f32x4 acc0[4][4], acc1[4][4];
    f32x4 z4 = {0.f, 0.f, 0.f, 0.f};
#pragma unroll
    for (int m = 0; m < 4; m++)
#pragma unroll
        for (int n = 0; n < 4; n++) { acc0[m][n] = z4; acc1[m][n] = z4; }

    for (int kt = 0; kt < DD / BK; ++kt) {
        int k0 = kt * BK;
        // 24 chunks of 1 KB (A:0-7, B0:8-15, B1:16-23); wave wv takes j*4+wv
#pragma unroll
        for (int j = 0; j < 6; ++j) {
            int c = j * 4 + wv;
            int tile = c >> 3;
            int lc = c & 7;
            int r = lc * 16 + ldr;
            const _Float16* src = (tile == 0) ? srcA : (tile == 1) ? srcB0 : srcB1;
            gld_lds16(src + (size_t)r * DD + k0 + ldc, &lds[c * 512]);
        }
        __syncthreads();

        half8 a[4], b0[4], b1[4];
#pragma unroll
        for (int m = 0; m < 4; m++)
            a[m] = *(const half8*)(&lds[(wm + m * 16 + l15) * BK + quad * 8]);
#pragma unroll
        for (int n = 0; n < 4; n++) {
            b0[n] = *(const half8*)(&lds[4096 + (wn + n * 16 + l15) * BK + quad * 8]);
            b1[n] = *(const half8*)(&lds[8192 + (wn + n * 16 + l15) * BK + quad * 8]);
        }
#pragma unroll
        for (int m = 0; m < 4; m++)
#pragma unroll
            for (int n = 0; n < 4; n++) {
                acc0[m][n] = __builtin_amdgcn_mfma_f32_16x16x32_f16(a[m], b0[n], acc0[m][n], 0, 0, 0);
                acc1[m][n] = __builtin_amdgcn_mfma_f32_16x16x32_f16(a[m], b1[n], acc1[m][n], 0, 0, 0);
            }
        __syncthreads();
    }

#pragma unroll
    for (int m = 0; m < 4; m++)
#pragma unroll
        for (int n = 0; n < 4; n++)
#pragma unroll
            for (int r = 0; r < 4; r++) {
                int row = row_base + wm + m * 16 + quad * 4 + r;
                int col = n_base + wn + n * 16 + l15;
                float y0 = acc0[m][n][r];
                float y1 = acc1[m][n][r];
                float v = y0 / (1.f + __expf(-y0)) * y1;
                act[(size_t)row * FF + col] = (_Float16)v;
            }
}

// w2 GEMM: C = act(M x F) @ W2(N x F)^T -> fp32 out.
// rowinfo==nullptr: plain store with row==token. else: atomicAdd scatter.
__global__ __launch_bounds__(256, 2)
void gemm_w2_kernel(const _Float16* __restrict__ Aact,
                    const _Float16* __restrict__ W2,
                    float* __restrict__ out,
                    const int* __restrict__ cnt,
                    const int* __restrict__ poff,
                    const int* __restrict__ rowinfo) {
    int row_base;
    const _Float16* w;
    if (cnt) {
        int e = blockIdx.z;
        int c = cnt[e];
        int mloc = blockIdx.y * BM;
        if (mloc >= c) return;
        row_base = poff[e] + mloc;
        w = W2 + (size_t)e * DD * FF;
    } else {
        row_base = blockIdx.y * BM;
        w = W2;
    }
    int n_base = blockIdx.x * 128;

    __shared__ _Float16 lds[128 * BK * 2];  // A | B = 16 KB

    const _Float16* srcA = Aact + (size_t)row_base * FF;
    const _Float16* srcB = w + (size_t)n_base * FF;

    int lane = threadIdx.x & 63;
    int wv = threadIdx.x >> 6;
    int wm = (wv >> 1) * 64;
    int wn = (wv & 1) * 64;
    int quad = lane >> 4;
    int l15 = lane & 15;
    int ldr = lane >> 2;
    int ldc = (lane & 3) * 8;

    f32x4 acc[4][4];
    f32x4 z4 = {0.f, 0.f, 0.f, 0.f};
#pragma unroll
    for (int m = 0; m < 4; m++)
#pragma unroll
        for (int n = 0; n < 4; n++) acc[m][n] = z4;

    for (int kt = 0; kt < FF / BK; ++kt) {
        int k0 = kt * BK;
        // 16 chunks of 1 KB (A:0-7, B:8-15); wave wv takes j*4+wv
#pragma unroll
        for (int j = 0; j < 4; ++j) {
            int c = j * 4 + wv;
            int tile = c >> 3;
            int lc = c & 7;
            int r = lc * 16 + ldr;
            const _Float16* src = (tile == 0) ? srcA : srcB;
            gld_lds16(src + (size_t)r * FF + k0 + ldc, &lds[c * 512]);
        }
        __syncthreads();

        half8 a[4], b[4];
#pragma unroll
        for (int m = 0; m < 4; m++)
            a[m] = *(const half8*)(&lds[(wm + m * 16 + l15) * BK + quad * 8]);
#pragma unroll
        for (int n = 0; n < 4; n++)
            b[n] = *(const half8*)(&lds[4096 + (wn + n * 16 + l15) * BK + quad * 8]);
#pragma unroll
        for (int m = 0; m < 4; m++)
#pragma unroll
            for (int n = 0; n < 4; n++)
                acc[m][n] = __builtin_amdgcn_mfma_f32_16x16x32_f16(a[m], b[n], acc[m][n], 0, 0, 0);
        __syncthreads();
    }

#pragma unroll
    for (int m = 0; m < 4; m++)
#pragma unroll
        for (int n = 0; n < 4; n++)
#pragma unroll
            for (int r = 0; r < 4; r++) {
                int row = row_base + wm + m * 16 + quad * 4 + r;
                int col = n_base + wn + n * 16 + l15;
                float v = acc[m][n][r];
                if (rowinfo) {
                    int t = rowinfo[row];
                    if (t >= 0) atomicAdd(&out[(size_t)t * DD + col], v);
                } else {
                    out[(size_t)row * DD + col] = v;
                }
            }
}

// ---------------- launch ----------------

extern "C" void kernel_launch(void* const* d_in, const int* in_sizes, int n_in,
                              void* d_out, int out_size, void* d_ws, size_t ws_size,
                              hipStream_t stream) {
    const float* x     = (const float*)d_in[0];   // 4096 x 2048
    const float* rDE   = (const float*)d_in[1];   // 2048 x 8
    const float* sw13  = (const float*)d_in[2];   // 4096 x 2048
    const float* sw2   = (const float*)d_in[3];   // 2048 x 2048
    const float* rw13  = (const float*)d_in[4];   // 8 x 4096 x 2048
    const float* rw2   = (const float*)d_in[5];   // 8 x 2048 x 2048
    float* out = (float*)d_out;

    char* ws = (char*)d_ws;
    size_t off = 0;
    auto alloc = [&](size_t bytes) {
        char* p = ws + off;
        off += (bytes + 255) & ~(size_t)255;
        return p;
    };
    _Float16* xh    = (_Float16*)alloc((size_t)TT * DD * 2);
    _Float16* sw13h = (_Float16*)alloc((size_t)2 * FF * DD * 2);
    _Float16* sw2h  = (_Float16*)alloc((size_t)DD * FF * 2);
    _Float16* rw13h = (_Float16*)alloc((size_t)EE * 2 * FF * DD * 2);
    _Float16* rw2h  = (_Float16*)alloc((size_t)EE * DD * FF * 2);
    _Float16* acts  = (_Float16*)alloc((size_t)TT * FF * 2);
    _Float16* gath  = (_Float16*)alloc((size_t)MAXPAD * DD * 2);
    _Float16* actr  = (_Float16*)alloc((size_t)MAXPAD * FF * 2);
    int* cnt        = (int*)alloc(EE * 4);
    int* poff       = (int*)alloc((EE + 1) * 4);
    int* tok_list   = (int*)alloc((size_t)EE * TT * 4);
    float* gate_list= (float*)alloc((size_t)EE * TT * 4);
    int* rowinfo    = (int*)alloc((size_t)MAXPAD * 4);

    zero_cnt_kernel<<<1, 64, 0, stream>>>(cnt);

    // fp32 -> fp16 conversions
    auto cvt = [&](const float* s, _Float16* d, int n) {
        cvt_f32_f16_kernel<<<(n / 4 + 255) / 256, 256, 0, stream>>>(s, d, n);
    };
    cvt(x,    xh,    TT * DD);
    cvt(sw13, sw13h, 2 * FF * DD);
    cvt(sw2,  sw2h,  DD * FF);
    cvt(rw13, rw13h, EE * 2 * FF * DD);
    cvt(rw2,  rw2h,  EE * DD * FF);

    router_topk_kernel<<<TT, 256, 0, stream>>>(x, rDE, cnt, tok_list, gate_list);
    scan_offsets_kernel<<<1, 64, 0, stream>>>(cnt, poff);
    gather_rows_kernel<<<MAXPAD, 256, 0, stream>>>(x, cnt, poff, tok_list, gate_list,
                                                   gath, rowinfo);

    // shared expert
    gemm_w13_swiglu_kernel<<<dim3(FF / 128, TT / 128, 1), 256, 0, stream>>>(
        xh, sw13h, acts, nullptr, nullptr);
    gemm_w2_kernel<<<dim3(DD / 128, TT / 128, 1), 256, 0, stream>>>(
        acts, sw2h, out, nullptr, nullptr, nullptr);

    // routed experts (grouped, early-exit tiles), scatter-add on top of shared out
    gemm_w13_swiglu_kernel<<<dim3(FF / 128, TT / 128, EE), 256, 0, stream>>>(
        gath, rw13h, actr, cnt, poff);
    gemm_w2_kernel<<<dim3(DD / 128, TT / 128, EE), 256, 0, stream>>>(
        actr, rw2h, out, cnt, poff, rowinfo);
}

// Round 3
// 1183.635 us; speedup vs baseline: 1.0115x; 1.0038x over previous
//
#include <hip/hip_runtime.h>
#include <hip/hip_fp16.h>
#include <stdint.h>

// Problem constants
#define TT 4096      // total tokens (B*T)
#define DD 2048      // model dim
#define FF 2048      // expert hidden dim
#define EE 8         // experts
#define BM 128
#define BK 32
#define MAXPAD 9216  // 8192 pairs + 8*128 pad

typedef _Float16 half8 __attribute__((ext_vector_type(8)));
typedef float f32x4 __attribute__((ext_vector_type(4)));

// Direct HBM -> LDS DMA, 16 B per lane, wave-uniform LDS base + lane*16.
__device__ inline void gld_lds16(const _Float16* g, _Float16* l) {
    __builtin_amdgcn_global_load_lds(
        (const __attribute__((address_space(1))) uint32_t*)g,
        (__attribute__((address_space(3))) uint32_t*)l, 16, 0, 0);
}

// XOR swizzle: k-group Q (16B) of tile row R lives at slot Q ^ ((R>>1)&3).
// Staging lane l (row-within-chunk = l>>2, slot = l&3) therefore fetches
// global k-group (l&3) ^ ((l>>3)&3); readers use quad ^ ((row>>1)&3).
// This spreads the 16-lane read phases over all 8 bank quads (2-way = free)
// instead of the unswizzled 8-way conflict on banks {0-3,16-19}.

// ---------------- utility kernels ----------------

__global__ void zero_cnt_kernel(int* cnt) {
    if (threadIdx.x < EE) cnt[threadIdx.x] = 0;
}

__global__ void cvt_f32_f16_kernel(const float* __restrict__ src,
                                   _Float16* __restrict__ dst, int n) {
    int i = (blockIdx.x * blockDim.x + threadIdx.x) * 4;
    if (i >= n) return;
    float4 v = *(const float4*)(src + i);
    union { _Float16 h[4]; uint2 u; } p;
    p.h[0] = (_Float16)v.x; p.h[1] = (_Float16)v.y;
    p.h[2] = (_Float16)v.z; p.h[3] = (_Float16)v.w;
    *(uint2*)(dst + i) = p.u;
}

// Router: scores = sigmoid(x @ router_DE), top-2, append to per-expert lists.
__global__ void router_topk_kernel(const float* __restrict__ x,
                                   const float* __restrict__ rDE,
                                   int* __restrict__ cnt,
                                   int* __restrict__ tok_list,
                                   float* __restrict__ gate_list) {
    int t = blockIdx.x;
    __shared__ float red[256 * EE];
    float part[EE];
#pragma unroll
    for (int e = 0; e < EE; e++) part[e] = 0.f;
    const float* xr = x + (size_t)t * DD;
    for (int d = threadIdx.x; d < DD; d += 256) {
        float xv = xr[d];
        const float* rr = rDE + (size_t)d * EE;
#pragma unroll
        for (int e = 0; e < EE; e++) part[e] += xv * rr[e];
    }
#pragma unroll
    for (int e = 0; e < EE; e++) red[threadIdx.x * EE + e] = part[e];
    __syncthreads();
    for (int s = 128; s > 0; s >>= 1) {
        if (threadIdx.x < s) {
#pragma unroll
            for (int e = 0; e < EE; e++)
                red[threadIdx.x * EE + e] += red[(threadIdx.x + s) * EE + e];
        }
        __syncthreads();
    }
    if (threadIdx.x == 0) {
        float sc[EE];
#pragma unroll
        for (int e = 0; e < EE; e++) sc[e] = 1.f / (1.f + expf(-red[e]));
        int i0 = 0;
        for (int e = 1; e < EE; e++) if (sc[e] > sc[i0]) i0 = e;
        int i1 = -1;
        for (int e = 0; e < EE; e++) {
            if (e == i0) continue;
            if (i1 < 0 || sc[e] > sc[i1]) i1 = e;
        }
        int p0 = atomicAdd(&cnt[i0], 1);
        tok_list[i0 * TT + p0] = t; gate_list[i0 * TT + p0] = sc[i0];
        int p1 = atomicAdd(&cnt[i1], 1);
        tok_list[i1 * TT + p1] = t; gate_list[i1 * TT + p1] = sc[i1];
    }
}

// Exclusive 128-padded offsets
__global__ void scan_offsets_kernel(const int* __restrict__ cnt, int* __restrict__ poff) {
    if (threadIdx.x == 0) {
        int off = 0;
        for (int e = 0; e < EE; e++) {
            poff[e] = off;
            off += ((cnt[e] + 127) >> 7) << 7;
        }
        poff[EE] = off;
    }
}

// Gather gate-scaled token rows into padded per-expert groups (fp16).
__global__ void gather_rows_kernel(const float* __restrict__ x,
                                   const int* __restrict__ cnt,
                                   const int* __restrict__ poff,
                                   const int* __restrict__ tok_list,
                                   const float* __restrict__ gate_list,
                                   _Float16* __restrict__ gath,
                                   int* __restrict__ rowinfo) {
    int b = blockIdx.x;
    if (b >= poff[EE]) return;
    int e = 0;
    while (b >= poff[e + 1]) e++;
    int i = b - poff[e];
    _Float16* dst = gath + (size_t)b * DD;
    if (i < cnt[e]) {
        int t = tok_list[e * TT + i];
        float g = gate_list[e * TT + i];
        if (threadIdx.x == 0) rowinfo[b] = t;
        const float* src = x + (size_t)t * DD;
        for (int d = threadIdx.x * 4; d < DD; d += 1024) {
            float4 v = *(const float4*)(src + d);
            union { _Float16 h[4]; uint2 u; } p;
            p.h[0] = (_Float16)(v.x * g); p.h[1] = (_Float16)(v.y * g);
            p.h[2] = (_Float16)(v.z * g); p.h[3] = (_Float16)(v.w * g);
            *(uint2*)(dst + d) = p.u;
        }
    } else {
        if (threadIdx.x == 0) rowinfo[b] = -1;
        uint2 z; z.x = 0u; z.y = 0u;
        for (int d = threadIdx.x * 4; d < DD; d += 1024)
            *(uint2*)(dst + d) = z;
    }
}

// ---------------- GEMM kernels ----------------
// C = A(M x 2048) @ W^T pattern: both operands row-major with K contiguous.
// fragment layouts (gfx950, 16x16x32): A/B: elem k = quad*8+j, m/n = lane&15
//                                      C/D: col = lane&15, row = quad*4+reg

// w13 GEMM: computes both halves (y0: W rows [0,F), y1: W rows [F,2F)) and
// writes act = silu(y0)*y1 as fp16.  If cnt!=nullptr: grouped (per-expert) mode.
__global__ __launch_bounds__(256, 2)
void gemm_w13_swiglu_kernel(const _Float16* __restrict__ A,
                            const _Float16* __restrict__ W13,
                            _Float16* __restrict__ act,
                            const int* __restrict__ cnt,
                            const int* __restrict__ poff) {
    int row_base;
    const _Float16* w;
    if (cnt) {
        int e = blockIdx.z;
        int c = cnt[e];
        int mloc = blockIdx.y * BM;
        if (mloc >= c) return;
        row_base = poff[e] + mloc;
        w = W13 + (size_t)e * (2 * FF) * DD;
    } else {
        row_base = blockIdx.y * BM;
        w = W13;
    }
    int n_base = blockIdx.x * 128;

    __shared__ _Float16 lds[128 * BK * 3];  // A | B0 | B1 = 24 KB

    const _Float16* srcA  = A + (size_t)row_base * DD;
    const _Float16* srcB0 = w + (size_t)n_base * DD;
    const _Float16* srcB1 = w + (size_t)(FF + n_base) * DD;

    int lane = threadIdx.x & 63;
    int wv = threadIdx.x >> 6;
    int wm = (wv >> 1) * 64;
    int wn = (wv & 1) * 64;
    int quad = lane >> 4;
    int l15 = lane & 15;
    int ldr = lane >> 2;                                // row-within-chunk for staging
    int ldc = ((lane & 3) ^ ((lane >> 3) & 3)) * 8;     // swizzled source k-group
    int qx = (quad ^ ((l15 >> 1) & 3)) * 8;             // swizzled read slot

    f32x4 acc0[4][4], acc1[4][4];
    f32x4 z4 = {0.f, 0.f, 0.f, 0.f};
#pragma unroll
    for (int m = 0; m < 4; m++)
#pragma unroll
        for (int n = 0; n < 4; n++) { acc0[m][n] = z4; acc1[m][n] = z4; }

    for (int kt = 0; kt < DD / BK; ++kt) {
        int k0 = kt * BK;
        // 24 chunks of 1 KB (A:0-7, B0:8-15, B1:16-23); wave wv takes j*4+wv
#pragma unroll
        for (int j = 0; j < 6; ++j) {
            int c = j * 4 + wv;
            int tile = c >> 3;
            int lc = c & 7;
            int r = lc * 16 + ldr;
            const _Float16* src = (tile == 0) ? srcA : (tile == 1) ? srcB0 : srcB1;
            gld_lds16(src + (size_t)r * DD + k0 + ldc, &lds[c * 512]);
        }
        __syncthreads();

        half8 a[4], b0[4], b1[4];
#pragma unroll
        for (int m = 0; m < 4; m++)
            a[m] = *(const half8*)(&lds[(wm + m * 16 + l15) * BK + qx]);
#pragma unroll
        for (int n = 0; n < 4; n++) {
            b0[n] = *(const half8*)(&lds[4096 + (wn + n * 16 + l15) * BK + qx]);
            b1[n] = *(const half8*)(&lds[8192 + (wn + n * 16 + l15) * BK + qx]);
        }
#pragma unroll
        for (int m = 0; m < 4; m++)
#pragma unroll
            for (int n = 0; n < 4; n++) {
                acc0[m][n] = __builtin_amdgcn_mfma_f32_16x16x32_f16(a[m], b0[n], acc0[m][n], 0, 0, 0);
                acc1[m][n] = __builtin_amdgcn_mfma_f32_16x16x32_f16(a[m], b1[n], acc1[m][n], 0, 0, 0);
            }
        __syncthreads();
    }

#pragma unroll
    for (int m = 0; m < 4; m++)
#pragma unroll
        for (int n = 0; n < 4; n++)
#pragma unroll
            for (int r = 0; r < 4; r++) {
                int row = row_base + wm + m * 16 + quad * 4 + r;
                int col = n_base + wn + n * 16 + l15;
                float y0 = acc0[m][n][r];
                float y1 = acc1[m][n][r];
                float v = y0 / (1.f + __expf(-y0)) * y1;
                act[(size_t)row * FF + col] = (_Float16)v;
            }
}

// w2 GEMM: C = act(M x F) @ W2(N x F)^T -> fp32 out.
// rowinfo==nullptr: plain store with row==token. else: atomicAdd scatter.
__global__ __launch_bounds__(256, 2)
void gemm_w2_kernel(const _Float16* __restrict__ Aact,
                    const _Float16* __restrict__ W2,
                    float* __restrict__ out,
                    const int* __restrict__ cnt,
                    const int* __restrict__ poff,
                    const int* __restrict__ rowinfo) {
    int row_base;
    const _Float16* w;
    if (cnt) {
        int e = blockIdx.z;
        int c = cnt[e];
        int mloc = blockIdx.y * BM;
        if (mloc >= c) return;
        row_base = poff[e] + mloc;
        w = W2 + (size_t)e * DD * FF;
    } else {
        row_base = blockIdx.y * BM;
        w = W2;
    }
    int n_base = blockIdx.x * 128;

    __shared__ _Float16 lds[128 * BK * 2];  // A | B = 16 KB

    const _Float16* srcA = Aact + (size_t)row_base * FF;
    const _Float16* srcB = w + (size_t)n_base * FF;

    int lane = threadIdx.x & 63;
    int wv = threadIdx.x >> 6;
    int wm = (wv >> 1) * 64;
    int wn = (wv & 1) * 64;
    int quad = lane >> 4;
    int l15 = lane & 15;
    int ldr = lane >> 2;
    int ldc = ((lane & 3) ^ ((lane >> 3) & 3)) * 8;
    int qx = (quad ^ ((l15 >> 1) & 3)) * 8;

    f32x4 acc[4][4];
    f32x4 z4 = {0.f, 0.f, 0.f, 0.f};
#pragma unroll
    for (int m = 0; m < 4; m++)
#pragma unroll
        for (int n = 0; n < 4; n++) acc[m][n] = z4;

    for (int kt = 0; kt < FF / BK; ++kt) {
        int k0 = kt * BK;
        // 16 chunks of 1 KB (A:0-7, B:8-15); wave wv takes j*4+wv
#pragma unroll
        for (int j = 0; j < 4; ++j) {
            int c = j * 4 + wv;
            int tile = c >> 3;
            int lc = c & 7;
            int r = lc * 16 + ldr;
            const _Float16* src = (tile == 0) ? srcA : srcB;
            gld_lds16(src + (size_t)r * FF + k0 + ldc, &lds[c * 512]);
        }
        __syncthreads();

        half8 a[4], b[4];
#pragma unroll
        for (int m = 0; m < 4; m++)
            a[m] = *(const half8*)(&lds[(wm + m * 16 + l15) * BK + qx]);
#pragma unroll
        for (int n = 0; n < 4; n++)
            b[n] = *(const half8*)(&lds[4096 + (wn + n * 16 + l15) * BK + qx]);
#pragma unroll
        for (int m = 0; m < 4; m++)
#pragma unroll
            for (int n = 0; n < 4; n++)
                acc[m][n] = __builtin_amdgcn_mfma_f32_16x16x32_f16(a[m], b[n], acc[m][n], 0, 0, 0);
        __syncthreads();
    }

#pragma unroll
    for (int m = 0; m < 4; m++)
#pragma unroll
        for (int n = 0; n < 4; n++)
#pragma unroll
            for (int r = 0; r < 4; r++) {
                int row = row_base + wm + m * 16 + quad * 4 + r;
                int col = n_base + wn + n * 16 + l15;
                float v = acc[m][n][r];
                if (rowinfo) {
                    int t = rowinfo[row];
                    if (t >= 0) atomicAdd(&out[(size_t)t * DD + col], v);
                } else {
                    out[(size_t)row * DD + col] = v;
                }
            }
}

// ---------------- launch ----------------

extern "C" void kernel_launch(void* const* d_in, const int* in_sizes, int n_in,
                              void* d_out, int out_size, void* d_ws, size_t ws_size,
                              hipStream_t stream) {
    const float* x     = (const float*)d_in[0];   // 4096 x 2048
    const float* rDE   = (const float*)d_in[1];   // 2048 x 8
    const float* sw13  = (const float*)d_in[2];   // 4096 x 2048
    const float* sw2   = (const float*)d_in[3];   // 2048 x 2048
    const float* rw13  = (const float*)d_in[4];   // 8 x 4096 x 2048
    const float* rw2   = (const float*)d_in[5];   // 8 x 2048 x 2048
    float* out = (float*)d_out;

    char* ws = (char*)d_ws;
    size_t off = 0;
    auto alloc = [&](size_t bytes) {
        char* p = ws + off;
        off += (bytes + 255) & ~(size_t)255;
        return p;
    };
    _Float16* xh    = (_Float16*)alloc((size_t)TT * DD * 2);
    _Float16* sw13h = (_Float16*)alloc((size_t)2 * FF * DD * 2);
    _Float16* sw2h  = (_Float16*)alloc((size_t)DD * FF * 2);
    _Float16* rw13h = (_Float16*)alloc((size_t)EE * 2 * FF * DD * 2);
    _Float16* rw2h  = (_Float16*)alloc((size_t)EE * DD * FF * 2);
    _Float16* acts  = (_Float16*)alloc((size_t)TT * FF * 2);
    _Float16* gath  = (_Float16*)alloc((size_t)MAXPAD * DD * 2);
    _Float16* actr  = (_Float16*)alloc((size_t)MAXPAD * FF * 2);
    int* cnt        = (int*)alloc(EE * 4);
    int* poff       = (int*)alloc((EE + 1) * 4);
    int* tok_list   = (int*)alloc((size_t)EE * TT * 4);
    float* gate_list= (float*)alloc((size_t)EE * TT * 4);
    int* rowinfo    = (int*)alloc((size_t)MAXPAD * 4);

    zero_cnt_kernel<<<1, 64, 0, stream>>>(cnt);

    // fp32 -> fp16 conversions
    auto cvt = [&](const float* s, _Float16* d, int n) {
        cvt_f32_f16_kernel<<<(n / 4 + 255) / 256, 256, 0, stream>>>(s, d, n);
    };
    cvt(x,    xh,    TT * DD);
    cvt(sw13, sw13h, 2 * FF * DD);
    cvt(sw2,  sw2h,  DD * FF);
    cvt(rw13, rw13h, EE * 2 * FF * DD);
    cvt(rw2,  rw2h,  EE * DD * FF);

    router_topk_kernel<<<TT, 256, 0, stream>>>(x, rDE, cnt, tok_list, gate_list);
    scan_offsets_kernel<<<1, 64, 0, stream>>>(cnt, poff);
    gather_rows_kernel<<<MAXPAD, 256, 0, stream>>>(x, cnt, poff, tok_list, gate_list,
                                                   gath, rowinfo);

    // shared expert
    gemm_w13_swiglu_kernel<<<dim3(FF / 128, TT / 128, 1), 256, 0, stream>>>(
        xh, sw13h, acts, nullptr, nullptr);
    gemm_w2_kernel<<<dim3(DD / 128, TT / 128, 1), 256, 0, stream>>>(
        acts, sw2h, out, nullptr, nullptr, nullptr);

    // routed experts (grouped, early-exit tiles), scatter-add on top of shared out
    gemm_w13_swiglu_kernel<<<dim3(FF / 128, TT / 128, EE), 256, 0, stream>>>(
        gath, rw13h, actr, cnt, poff);
    gemm_w2_kernel<<<dim3(DD / 128, TT / 128, EE), 256, 0, stream>>>(
        actr, rw2h, out, cnt, poff, rowinfo);
}